// Round 12
// baseline (231.202 us; speedup 1.0000x reference)
//
#include <hip/hip_runtime.h>
#include <hip/hip_bf16.h>
#include <math.h>

using bf16 = __hip_bfloat16;
typedef short bf16x8 __attribute__((ext_vector_type(8)));
typedef float f32x4 __attribute__((ext_vector_type(4)));

#define GAMMA_LOG2 (-0.0014434688536725045f)  // log2(0.999)

union Bf16Bits { bf16 h; unsigned short s; };
union VecU { uint4 q; unsigned short s[8]; };

__device__ inline unsigned short bf16_bits(float z)
{
    Bf16Bits u;
    u.h = __float2bfloat16(z);
    return u.s;
}

__device__ inline unsigned int packbf2(float a, float b)
{
    return (unsigned int)bf16_bits(a) | ((unsigned int)bf16_bits(b) << 16);
}

// async global->LDS, 16 B per lane. LDS dest is wave-uniform base + lane*16.
__device__ __forceinline__ void async_copy16(unsigned short* lds, const bf16* g)
{
    __builtin_amdgcn_global_load_lds(
        (const __attribute__((address_space(1))) unsigned int*)(const void*)g,
        (__attribute__((address_space(3))) unsigned int*)(void*)lds,
        16, 0, 0);
}

// ---------- fused prologue: weight transposes + MLP weight prep + rms(x) ----------
// v13: k_prep (1536 blocks) + k_prep_mlp (640) + k_rms_x (8192) were three
// short serial launches; block-range dispatch overlaps all three legs.
struct PrepArgs {
    const float* src[3];
    bf16* dst[3];
    int R[3];
    int C[3];
    int pfx[4];
};

__global__ void k_prologue(PrepArgs pa,
                           const float* __restrict__ W1, const float* __restrict__ W2,
                           const float* __restrict__ W3, const float* __restrict__ Wz,
                           bf16* __restrict__ Wf,
                           const float* __restrict__ x, bf16* __restrict__ xn)
{
    const int bidg = blockIdx.x;
    if (bidg < 1536) {
        // ---- leg 1: 3 fp32 (R x C) -> bf16 (C x R) transposes ----
        __shared__ float tile[32][33];
        int bid = bidg;
        int seg = 0;
        while (bid >= pa.pfx[seg + 1]) ++seg;
        int local = bid - pa.pfx[seg];
        int R = pa.R[seg], C = pa.C[seg];
        int ctiles = C >> 5;
        int c0 = (local % ctiles) * 32, r0 = (local / ctiles) * 32;
        const float* in = pa.src[seg];
        bf16* out = pa.dst[seg];
        int tx = threadIdx.x & 31, ty = threadIdx.x >> 5;
#pragma unroll
        for (int i = 0; i < 4; ++i) {
            int r = r0 + ty + 8 * i;
            tile[ty + 8 * i][tx] = in[(size_t)r * C + c0 + tx];
        }
        __syncthreads();
#pragma unroll
        for (int i = 0; i < 4; ++i) {
            int cc = c0 + ty + 8 * i, rr = r0 + tx;
            out[(size_t)cc * R + rr] = __float2bfloat16(tile[tx][ty + 8 * i]);
        }
        return;
    }
    if (bidg < 2176) {
        // ---- leg 2: MLP weights -> fragment-major ----
        int g = (bidg - 1536) * 256 + threadIdx.x;   // 163840 threads
        int unit = g >> 15;
        int idx = g & 32767;
        int lane = idx & 63;
        int nj = (idx >> 6) & 7;
        int ks = (idx >> 9) & 15;
        int wc = idx >> 13;
        int lm = lane & 15, lq = lane >> 4;
        int k0 = ks * 32 + lq * 8;
        const float* src;
        int N, o;
        if (unit < 3) {
            src = (unit == 0) ? W1 : (unit == 1) ? W2 : W3;
            N = 512;
            o = wc * 128 + nj * 16 + lm;
        } else {
            src = Wz;
            N = 1024;
            o = (unit - 3) * 512 + wc * 128 + nj * 16 + lm;
        }
        VecU v;
#pragma unroll
        for (int j = 0; j < 8; ++j)
            v.s[j] = bf16_bits(src[(size_t)(k0 + j) * N + o]);
        *(uint4*)(void*)(Wf + (size_t)g * 8) = v.q;
        return;
    }
    // ---- leg 3: x -> srms(x) bf16, one row of 512 per block ----
    {
        int row = bidg - 2176, t = threadIdx.x;
        const float* xr = x + (size_t)row * 512;
        float a = xr[t], b = xr[t + 256];
        float v = a * a + b * b;
#pragma unroll
        for (int m = 32; m >= 1; m >>= 1) v += __shfl_xor(v, m, 64);
        __shared__ float ws[4];
        if ((t & 63) == 0) ws[t >> 6] = v;
        __syncthreads();
        float tot = ws[0] + ws[1] + ws[2] + ws[3];
        float s = 1.f / (sqrtf(tot * (1.f / 512.f)) + 1e-8f);
        bf16* o = xn + (size_t)row * 512;
        o[t] = __float2bfloat16(a * s);
        o[t + 256] = __float2bfloat16(b * s);
    }
}

// ---------- gate + transpose, vectorized (64x64 uint4 tiles) ----------
__global__ void k_gate_transpose(const bf16* __restrict__ ud1t, const bf16* __restrict__ uv,
                                 bf16* __restrict__ out)
{
    __shared__ unsigned short tile[64][65];
    const int b = blockIdx.z;
    const int t = threadIdx.x;
    int c0 = blockIdx.x * 64, t0 = blockIdx.y * 64;
#pragma unroll
    for (int it = 0; it < 2; ++it) {
        int r = it * 32 + (t >> 3), cc = (t & 7) * 8;   // r: channel row, cc: t chunk
        VecU v;
        v.q = *(const uint4*)(const void*)(ud1t + ((size_t)b * 1024 + c0 + r) * 2048 + t0 + cc);
#pragma unroll
        for (int i = 0; i < 8; ++i) tile[r][cc + i] = v.s[i];
    }
    __syncthreads();
#pragma unroll
    for (int it = 0; it < 2; ++it) {
        int tt = it * 32 + (t >> 3), cc = (t & 7) * 8;  // tt: time row, cc: channel chunk
        VecU vu;
        vu.q = *(const uint4*)(const void*)(uv + ((size_t)b * 2048 + t0 + tt) * 2048 + c0 + cc);
        VecU vo;
#pragma unroll
        for (int i = 0; i < 8; ++i) {
            Bf16Bits cv, uu;
            cv.s = tile[cc + i][tt];
            uu.s = vu.s[i];
            vo.s[i] = bf16_bits(__bfloat162float(cv.h) * __bfloat162float(uu.h));
        }
        *(uint4*)(void*)(out + ((size_t)b * 2048 + t0 + tt) * 1024 + c0 + cc) = vo.q;
    }
}

// ---------- positional MLP: 64 blocks x 1024 threads (16 waves) ----------
// v13: final layer writes atb[col][pos] DIRECTLY (uint2 of 4 consecutive pos
// per fragment) — each (col, block) pair covers a contiguous 64-B run filled
// by one wave burst, so writes are full-sector. Eliminates the ab buffer and
// the k_transpose_a kernel entirely.
__global__ __launch_bounds__(1024, 1) void k_mlp(
    const float* __restrict__ Wp, const float* __restrict__ bp,
    const bf16* __restrict__ Wf,
    const float* __restrict__ b1, const float* __restrict__ b2,
    const float* __restrict__ b3, const float* __restrict__ bz,
    bf16* __restrict__ atb)
{
    __shared__ unsigned short X[32][520];
    __shared__ float sq2[32][33];
    __shared__ float red[16][32];
    __shared__ float scale[32];

    const int tid = threadIdx.x, lane = tid & 63, w = tid >> 6;   // w 0..15
    const int lm = lane & 15, lq = lane >> 4;
    const int posBase = blockIdx.x * 32;

    // stage 0: X[r][:] = relu(srms(pos*Wp + bp)); 1024 threads = 32 rows x 32 chunks
    {
        const int r = tid >> 5;            // 0..31
        const int cb = tid & 31;           // 0..31
        const int c0 = cb * 16;
        float vals[16];
        float ssq = 0.f;
        const float fp = (float)(posBase + r);
#pragma unroll
        for (int e = 0; e < 16; ++e) {
            float z = fp * Wp[c0 + e] + bp[c0 + e];
            vals[e] = z;
            ssq += z * z;
        }
        sq2[r][cb] = ssq;
        __syncthreads();
        float tot = 0.f;
#pragma unroll
        for (int i = 0; i < 32; ++i) tot += sq2[r][i];
        float s = 1.f / (sqrtf(tot * (1.f / 512.f)) + 1e-8f);
        unsigned int* xrow = (unsigned int*)&X[r][c0];
#pragma unroll
        for (int e = 0; e < 8; ++e)
            xrow[e] = packbf2(fmaxf(vals[2 * e] * s, 0.f), fmaxf(vals[2 * e + 1] * s, 0.f));
        __syncthreads();
    }

    const int wc = w >> 2, njb = (w & 3) * 2;   // wave's 32-col slice

    // one 512-K GEMM pass; static 4-deep rotation with named register buffers
    auto layer_mm = [&](const bf16* Wu_, f32x4 (&acc)[2][2]) {
        const bf16* base = Wu_ + (size_t)wc * 65536 + (size_t)njb * 512 + (size_t)lane * 8;
        bf16x8 B0[2], B1[2], B2[2], B3[2];
#define LOADB(DST, KS)                                                        \
        DST[0] = *(const bf16x8*)(const void*)(base + (KS) * 4096);           \
        DST[1] = *(const bf16x8*)(const void*)(base + (KS) * 4096 + 512);
#define MMST(BUF, KS) {                                                       \
        bf16x8 af0 = *(const bf16x8*)(const void*)&X[lm][(KS) * 32 + lq * 8]; \
        bf16x8 af1 = *(const bf16x8*)(const void*)&X[16 + lm][(KS) * 32 + lq * 8]; \
        acc[0][0] = __builtin_amdgcn_mfma_f32_16x16x32_bf16(af0, BUF[0], acc[0][0], 0, 0, 0); \
        acc[0][1] = __builtin_amdgcn_mfma_f32_16x16x32_bf16(af0, BUF[1], acc[0][1], 0, 0, 0); \
        acc[1][0] = __builtin_amdgcn_mfma_f32_16x16x32_bf16(af1, BUF[0], acc[1][0], 0, 0, 0); \
        acc[1][1] = __builtin_amdgcn_mfma_f32_16x16x32_bf16(af1, BUF[1], acc[1][1], 0, 0, 0); }
        LOADB(B0, 0)  LOADB(B1, 1)  LOADB(B2, 2)
        LOADB(B3, 3)  MMST(B0, 0)
        LOADB(B0, 4)  MMST(B1, 1)
        LOADB(B1, 5)  MMST(B2, 2)
        LOADB(B2, 6)  MMST(B3, 3)
        LOADB(B3, 7)  MMST(B0, 4)
        LOADB(B0, 8)  MMST(B1, 5)
        LOADB(B1, 9)  MMST(B2, 6)
        LOADB(B2, 10) MMST(B3, 7)
        LOADB(B3, 11) MMST(B0, 8)
        LOADB(B0, 12) MMST(B1, 9)
        LOADB(B1, 13) MMST(B2, 10)
        LOADB(B2, 14) MMST(B3, 11)
        LOADB(B3, 15) MMST(B0, 12)
        MMST(B1, 13)
        MMST(B2, 14)
        MMST(B3, 15)
#undef LOADB
#undef MMST
    };

    const float* bs[3] = {b1, b2, b3};
    for (int l = 0; l < 3; ++l) {
        f32x4 acc[2][2];
#pragma unroll
        for (int mi = 0; mi < 2; ++mi)
#pragma unroll
            for (int i = 0; i < 2; ++i) acc[mi][i] = (f32x4){0.f, 0.f, 0.f, 0.f};
        layer_mm(Wf + (size_t)l * 262144, acc);
        // bias BEFORE srms
#pragma unroll
        for (int mi = 0; mi < 2; ++mi)
#pragma unroll
            for (int nj = 0; nj < 2; ++nj) {
                float bb = bs[l][w * 32 + nj * 16 + lm];
#pragma unroll
                for (int r = 0; r < 4; ++r) acc[mi][nj][r] += bb;
            }
        float pr[2][4] = {{0.f, 0.f, 0.f, 0.f}, {0.f, 0.f, 0.f, 0.f}};
#pragma unroll
        for (int mi = 0; mi < 2; ++mi)
#pragma unroll
            for (int nj = 0; nj < 2; ++nj)
#pragma unroll
                for (int r = 0; r < 4; ++r) pr[mi][r] += acc[mi][nj][r] * acc[mi][nj][r];
#pragma unroll
        for (int m = 1; m < 16; m <<= 1)
#pragma unroll
            for (int mi = 0; mi < 2; ++mi)
#pragma unroll
                for (int r = 0; r < 4; ++r) pr[mi][r] += __shfl_xor(pr[mi][r], m);
        if (lm == 0)
#pragma unroll
            for (int mi = 0; mi < 2; ++mi)
#pragma unroll
                for (int r = 0; r < 4; ++r) red[w][mi * 16 + lq * 4 + r] = pr[mi][r];
        __syncthreads();   // also: all waves done reading X for this layer
        if (tid < 32) {
            float tot = 0.f;
#pragma unroll
            for (int wv = 0; wv < 16; ++wv) tot += red[wv][tid];
            scale[tid] = 1.f / (sqrtf(tot * (1.f / 512.f)) + 1e-8f);
        }
        __syncthreads();
#pragma unroll
        for (int mi = 0; mi < 2; ++mi)
#pragma unroll
            for (int nj = 0; nj < 2; ++nj) {
                int col = w * 32 + nj * 16 + lm;
#pragma unroll
                for (int r = 0; r < 4; ++r) {
                    int row = mi * 16 + lq * 4 + r;
                    float z = fmaxf(acc[mi][nj][r] * scale[row], 0.f);
                    *(unsigned short*)&X[row][col] = bf16_bits(z);
                }
            }
        __syncthreads();
    }

    // final layer: Wz as two fragment-major 512-col units; +bz, *gamma^pos;
    // write straight into atb[col][pos] (transposed layout, uint2 runs)
#pragma unroll
    for (int h = 0; h < 2; ++h) {
        f32x4 acc[2][2];
#pragma unroll
        for (int mi = 0; mi < 2; ++mi)
#pragma unroll
            for (int i = 0; i < 2; ++i) acc[mi][i] = (f32x4){0.f, 0.f, 0.f, 0.f};
        layer_mm(Wf + (size_t)(3 + h) * 262144, acc);
#pragma unroll
        for (int mi = 0; mi < 2; ++mi)
#pragma unroll
            for (int nj = 0; nj < 2; ++nj) {
                int col = h * 512 + w * 32 + nj * 16 + lm;
                float bb = bz[col];
                int pos0 = posBase + mi * 16 + lq * 4;
                float zs[4];
#pragma unroll
                for (int r = 0; r < 4; ++r)
                    zs[r] = (acc[mi][nj][r] + bb) * exp2f((float)(pos0 + r) * GAMMA_LOG2);
                uint2 o;
                o.x = packbf2(zs[0], zs[1]);
                o.y = packbf2(zs[2], zs[3]);
                *(uint2*)(void*)(atb + (size_t)col * 2048 + pos0) = o;
            }
    }
}

// ---------- uv GEMM: u -> uvb (t,c); v -> vtb (b,c,t) via LDS-staged transpose ----------
__global__ __launch_bounds__(256, 4) void k_uv(
    const bf16* __restrict__ A, const bf16* __restrict__ Bt,   // xn, Wuvt
    const float* __restrict__ bu, const float* __restrict__ bv,
    bf16* __restrict__ uvb, bf16* __restrict__ vtb)
{
    __shared__ unsigned short AB[2][2][128 * 32];   // [buf][A|B] 32 KB

    const int tid = threadIdx.x, lane = tid & 63, w = tid >> 6;
    const int lm = lane & 15, lq = lane >> 4;
    const int gid = blockIdx.x;
    const int wm = (w >> 1) * 64, wn = (w & 1) * 64;
    const long rowBase = (long)(gid & 63) * 128, colBase = (long)(gid >> 6) * 128;

    const int srow = tid >> 2;                        // 0..63
    const int sqz  = (tid & 3) ^ ((srow >> 1) & 3);   // swizzled k-chunk
    const bf16* gA  = A  + (rowBase + srow) * 512 + sqz * 8;
    const bf16* gB  = Bt + (colBase + srow) * 512 + sqz * 8;
    const bf16* gA2 = gA + (size_t)64 * 512;
    const bf16* gB2 = gB + (size_t)64 * 512;
    const int ls0 = w * 512;
    const int ls1 = 2048 + w * 512;

    const int rdA = ((wm + lm) * 4 + (lq ^ ((lm >> 1) & 3))) * 8;
    const int rdB = ((wn + lm) * 4 + (lq ^ ((lm >> 1) & 3))) * 8;

    f32x4 acc[4][4];
    f32x4 zz = {0.f, 0.f, 0.f, 0.f};
#pragma unroll
    for (int i = 0; i < 4; ++i)
#pragma unroll
        for (int j = 0; j < 4; ++j) acc[i][j] = zz;

    async_copy16(&AB[0][0][ls0], gA);
    async_copy16(&AB[0][0][ls1], gA2);
    async_copy16(&AB[0][1][ls0], gB);
    async_copy16(&AB[0][1][ls1], gB2);
    __syncthreads();

#pragma unroll
    for (int t = 0; t < 16; ++t) {
        const int cur = t & 1;
        if (t < 15) {
            const int kk = (t + 1) * 32;
            async_copy16(&AB[cur ^ 1][0][ls0], gA + kk);
            async_copy16(&AB[cur ^ 1][0][ls1], gA2 + kk);
            async_copy16(&AB[cur ^ 1][1][ls0], gB + kk);
            async_copy16(&AB[cur ^ 1][1][ls1], gB2 + kk);
        }
        bf16x8 af[4], bfr[4];
#pragma unroll
        for (int mi = 0; mi < 4; ++mi)
            af[mi] = *(const bf16x8*)(const void*)&AB[cur][0][rdA + mi * 512];
#pragma unroll
        for (int nj = 0; nj < 4; ++nj)
            bfr[nj] = *(const bf16x8*)(const void*)&AB[cur][1][rdB + nj * 512];
#pragma unroll
        for (int mi = 0; mi < 4; ++mi)
#pragma unroll
            for (int nj = 0; nj < 4; ++nj)
                acc[mi][nj] = __builtin_amdgcn_mfma_f32_16x16x32_bf16(af[mi], bfr[nj], acc[mi][nj], 0, 0, 0);
        if (t < 15) __syncthreads();
    }

    const bool vhalf = colBase >= 1024;   // block-uniform
    if (!vhalf) {
#pragma unroll
        for (int mi = 0; mi < 4; ++mi)
#pragma unroll
            for (int nj = 0; nj < 4; ++nj) {
                long col = colBase + wn + nj * 16 + lm;
                float bb = bu[col];
                long row0 = rowBase + wm + mi * 16 + lq * 4;
#pragma unroll
                for (int r = 0; r < 4; ++r) {
                    float z = acc[mi][nj][r] + bb;
                    z = z / (1.f + __expf(-z));
                    uvb[(size_t)(row0 + r) * 2048 + col] = __float2bfloat16(z);
                }
            }
    } else {
        __syncthreads();   // all waves done reading AB
        unsigned short* sh = &AB[0][0][0];   // 128 x 128 shorts, rotation-swizzled
#pragma unroll
        for (int mi = 0; mi < 4; ++mi)
#pragma unroll
            for (int nj = 0; nj < 4; ++nj) {
                int c_local = wn + nj * 16 + lm;
                float bb = bv[colBase - 1024 + c_local];
                int t_local = wm + mi * 16 + lq * 4;
                float zs[4];
#pragma unroll
                for (int r = 0; r < 4; ++r) {
                    float z = acc[mi][nj][r] + bb;
                    zs[r] = z / (1.f + __expf(-z));
                }
                int p = (t_local + 8 * c_local) & 127;
                uint2 o;
                o.x = packbf2(zs[0], zs[1]);
                o.y = packbf2(zs[2], zs[3]);
                *(uint2*)(void*)&sh[c_local * 128 + p] = o;
            }
        __syncthreads();
        const int b   = (int)(rowBase >> 11);
        const int tb0 = (int)(rowBase & 2047);
        const long cb = colBase - 1024;
        const int cl = tid >> 4;    // 0..15
        const int ch = tid & 15;    // 16-B chunk along t
#pragma unroll
        for (int it = 0; it < 8; ++it) {
            int c_local = it * 16 + cl;
            int p = (ch * 8 + 8 * c_local) & 127;
            uint4 q = *(const uint4*)(const void*)&sh[c_local * 128 + p];
            *(uint4*)(void*)(vtb + ((size_t)b * 1024 + cb + c_local) * 2048 + tb0 + ch * 8) = q;
        }
    }
}

// ---------- out projection GEMM v2: async dbuf, 1 barrier/step, 64x128 tile ----------
__global__ __launch_bounds__(256, 4) void k_gemm_out2(
    const bf16* __restrict__ A, const bf16* __restrict__ Bt,
    const float* __restrict__ bias0, const float* __restrict__ addsrc,
    float* __restrict__ outp)
{
    __shared__ unsigned short As[2][64 * 32];    // 8 KB
    __shared__ unsigned short Bs[2][128 * 32];   // 16 KB

    const int tid = threadIdx.x, lane = tid & 63, w = tid >> 6;
    const int lm = lane & 15, lq = lane >> 4;
    const int wm = (w >> 1) * 32, wn = (w & 1) * 64;   // wave: 32 rows x 64 cols
    const long rowBase = (long)blockIdx.x * 64, colBase = (long)blockIdx.y * 128;

    const int srow = tid >> 2;                        // 0..63
    const int sqz  = (tid & 3) ^ ((srow >> 1) & 3);   // swizzled k-chunk
    const bf16* gA  = A  + (rowBase + srow) * 1024 + sqz * 8;
    const bf16* gB  = Bt + (colBase + srow) * 1024 + sqz * 8;
    const bf16* gB2 = gB + (size_t)64 * 1024;
    const int lsA = w * 512;
    const int lsB0 = w * 512, lsB1 = 2048 + w * 512;

    const int rdA = ((wm + lm) * 4 + (lq ^ ((lm >> 1) & 3))) * 8;
    const int rdB = ((wn + lm) * 4 + (lq ^ ((lm >> 1) & 3))) * 8;

    f32x4 acc[2][4];
    f32x4 zz = {0.f, 0.f, 0.f, 0.f};
#pragma unroll
    for (int i = 0; i < 2; ++i)
#pragma unroll
        for (int j = 0; j < 4; ++j) acc[i][j] = zz;

    async_copy16(&As[0][lsA], gA);
    async_copy16(&Bs[0][lsB0], gB);
    async_copy16(&Bs[0][lsB1], gB2);
    __syncthreads();

#pragma unroll
    for (int t = 0; t < 32; ++t) {
        const int cur = t & 1;
        if (t < 31) {
            const int kk = (t + 1) * 32;
            async_copy16(&As[cur ^ 1][lsA], gA + kk);
            async_copy16(&Bs[cur ^ 1][lsB0], gB + kk);
            async_copy16(&Bs[cur ^ 1][lsB1], gB2 + kk);
        }
        bf16x8 af[2], bfr[4];
#pragma unroll
        for (int mi = 0; mi < 2; ++mi)
            af[mi] = *(const bf16x8*)(const void*)&As[cur][rdA + mi * 512];
#pragma unroll
        for (int nj = 0; nj < 4; ++nj)
            bfr[nj] = *(const bf16x8*)(const void*)&Bs[cur][rdB + nj * 512];
#pragma unroll
        for (int mi = 0; mi < 2; ++mi)
#pragma unroll
            for (int nj = 0; nj < 4; ++nj)
                acc[mi][nj] = __builtin_amdgcn_mfma_f32_16x16x32_bf16(af[mi], bfr[nj], acc[mi][nj], 0, 0, 0);
        if (t < 31) __syncthreads();
    }

#pragma unroll
    for (int mi = 0; mi < 2; ++mi)
#pragma unroll
        for (int nj = 0; nj < 4; ++nj) {
            long col = colBase + wn + nj * 16 + lm;
            float bb = bias0[col];
#pragma unroll
            for (int r = 0; r < 4; ++r) {
                long row = rowBase + wm + mi * 16 + lq * 4 + r;
                size_t off = (size_t)row * 512 + col;
                outp[off] = acc[mi][nj][r] + bb + addsrc[off];
            }
        }
}

// ---------- Toeplitz-MFMA depthwise causal conv (v4, diagonal-reuse) ----------
__global__ __launch_bounds__(256, 4) void k_conv_mfma(
    const bf16* __restrict__ vt, const bf16* __restrict__ at, bf16* __restrict__ ud1t)
{
    __shared__ unsigned short ash2[2][2068];  // reversed filter, 2 shifted copies
    __shared__ unsigned short vsh[4][3072];   // per-batch v, stride 24 per 16-elem tile

    const int tid = threadIdx.x, lane = tid & 63, w = tid >> 6;
    const int c = blockIdx.x;

    {
        const unsigned short* asrc = (const unsigned short*)(at + (size_t)c * 2048);
        for (int i = tid; i < 2068; i += 256) {
#pragma unroll
            for (int k = 0; k < 2; ++k) {
                int src = 2047 - i - k;
                ash2[k][i] = (src >= 0) ? asrc[src] : (unsigned short)0;
            }
        }
    }
    {
        const bf16* vsrc = vt + ((size_t)w * 1024 + c) * 2048;
#pragma unroll
        for (int q = 0; q < 4; ++q) {
            int li = q * 64 + lane;
            int tile = li >> 1, hf = li & 1;
            *(uint4*)(void*)&vsh[w][tile * 24 + hf * 8] =
                *(const uint4*)(const void*)(vsrc + li * 8);
        }
    }
    __syncthreads();

    const int lm = lane & 15, lq = lane >> 4;
    const int h = lq >> 1, p0 = (lq & 1) * 8;
    const int kcopy = (lm + 1) & 1;
    const int base = 31 - 16 * h - lm + p0 - kcopy;
    const unsigned int* aw = (const unsigned int*)(void*)&ash2[kcopy][0] + (base >> 1);
    const unsigned short* vw = &vsh[w][0];

    f32x4 acc[8];
    f32x4 zz = {0.f, 0.f, 0.f, 0.f};
#pragma unroll
    for (int i = 0; i < 8; ++i) acc[i] = zz;
    const bf16x8 zfrag = (bf16x8)(short)0;

    for (int d2 = 0; d2 < 16; d2 += 2) {
        bf16x8 vf[8];
        const int tb = lm - d2 - h;
        {
            int T = tb > 0 ? tb : 0;
            bf16x8 f = *(const bf16x8*)(const void*)(vw + T * 24 + p0);
            vf[0] = (tb < 0) ? zfrag : f;
        }
#pragma unroll
        for (int dl = 1; dl < 8; ++dl)
            vf[dl] = *(const bf16x8*)(const void*)(vw + (dl * 16 + tb) * 24 + p0);

#pragma unroll
        for (int dt = 0; dt < 8; ++dt) {
            const int m16 = (63 - ((dt * 16 + d2) >> 1)) * 16;
            union { unsigned int u[4]; bf16x8 v; } af;
            af.u[0] = aw[m16 + 0];
            af.u[1] = aw[m16 + 1];
            af.u[2] = aw[m16 + 2];
            af.u[3] = aw[m16 + 3];
#pragma unroll
            for (int dl = 0; dl < 8 - dt; ++dl)
                acc[dt + dl] = __builtin_amdgcn_mfma_f32_16x16x32_bf16(af.v, vf[dl], acc[dt + dl], 0, 0, 0);
        }
    }

    __syncthreads();
    float* stg = (float*)(void*)((char*)(void*)&ash2[0][0] + w * 1024);
    bf16* dst = ud1t + ((size_t)w * 1024 + c) * 2048;
#pragma unroll
    for (int jg = 0; jg < 8; ++jg) {
        *(f32x4*)(void*)&stg[lm * 16 + lq * 4] = acc[jg];
        f32x4 vv = *(const f32x4*)(const void*)&stg[lane * 4];
        uint2 o;
        o.x = packbf2(vv.x, vv.y);
        o.y = packbf2(vv.z, vv.w);
        *(uint2*)(void*)(dst + jg * 256 + lane * 4) = o;
    }
}

extern "C" void kernel_launch(void* const* d_in, const int* in_sizes, int n_in,
                              void* d_out, int out_size, void* d_ws, size_t ws_size,
                              hipStream_t stream)
{
    const float* x  = (const float*)d_in[0];
    const float* Wu = (const float*)d_in[1];
    const float* bu = (const float*)d_in[2];
    const float* Wv = (const float*)d_in[3];
    const float* bv = (const float*)d_in[4];
    const float* Wo = (const float*)d_in[5];
    const float* bo = (const float*)d_in[6];
    const float* Wp = (const float*)d_in[7];
    const float* bp = (const float*)d_in[8];
    const float* W1 = (const float*)d_in[9];
    const float* b1 = (const float*)d_in[10];
    const float* W2 = (const float*)d_in[11];
    const float* b2 = (const float*)d_in[12];
    const float* W3 = (const float*)d_in[13];
    const float* b3 = (const float*)d_in[14];
    const float* Wz = (const float*)d_in[15];
    const float* bz = (const float*)d_in[16];

    char* p = (char*)d_ws;
    auto carve = [&](size_t bytes) { void* q = (void*)p; p += (bytes + 255) & ~(size_t)255; return q; };
    bf16*  xn   = (bf16*)carve((size_t)8192 * 512 * 2);
    bf16*  Wuvt = (bf16*)carve((size_t)2048 * 512 * 2);
    bf16*  Wot  = (bf16*)carve((size_t)512 * 1024 * 2);
    bf16*  Wf   = (bf16*)carve((size_t)5 * 262144 * 2);       // fragment-major MLP weights
    bf16*  uvb  = (bf16*)carve((size_t)8192 * 2048 * 2);      // u silu output (t, c); v-half unused
    bf16*  ud1  = (bf16*)carve((size_t)8192 * 1024 * 2);      // u * conv, (t, c)
    bf16*  vtb  = (bf16*)carve((size_t)4 * 1024 * 2048 * 2);  // v (b,c,t) — written by k_uv
    bf16*  atb  = (bf16*)carve((size_t)1024 * 2048 * 2);      // a (c,k) — written by k_mlp
    bf16*  ud1t = (bf16*)carve((size_t)4 * 1024 * 2048 * 2);  // conv result (b,c,t)

    // fused prologue: weight transposes + MLP weight prep + rms(x)
    PrepArgs pa;
    const float* srcs[3] = {Wu, Wv, Wo};
    bf16* dsts[3] = {Wuvt, Wuvt + (size_t)1024 * 512, Wot};
    int Rs[3] = {512, 512, 1024};
    int Cs[3] = {1024, 1024, 512};
    int acc_t = 0;
    for (int i = 0; i < 3; ++i) {
        pa.src[i] = srcs[i]; pa.dst[i] = dsts[i]; pa.R[i] = Rs[i]; pa.C[i] = Cs[i];
        pa.pfx[i] = acc_t;
        acc_t += (Rs[i] / 32) * (Cs[i] / 32);
    }
    pa.pfx[3] = acc_t;  // 1536
    k_prologue<<<1536 + 640 + 8192, 256, 0, stream>>>(pa, W1, W2, W3, Wz, Wf, x, xn);

    // positional MLP (writes atb directly, transposed)
    k_mlp<<<64, 1024, 0, stream>>>(Wp, bp, Wf, b1, b2, b3, bz, atb);

    // uv: u -> uvb (t,c), v -> vtb (b,c,t) via LDS-staged coalesced writes
    k_uv<<<1024, 256, 0, stream>>>(xn, Wuvt, bu, bv, uvb, vtb);

    // causal depthwise conv via Toeplitz-MFMA (block = channel x 4 batches)
    k_conv_mfma<<<dim3(1024), 256, 0, stream>>>(vtb, atb, ud1t);

    // gate by u and transpose back to (t, c) — vectorized
    k_gate_transpose<<<dim3(16, 32, 4), 256, 0, stream>>>(ud1t, uvb, ud1);

    // y = ud1 @ Wo + bo + x  (async dbuf structure, 512 blocks)
    k_gemm_out2<<<dim3(128, 4), 256, 0, stream>>>(ud1, Wot, bo, x, (float*)d_out);
}

// Round 13
// 210.929 us; speedup vs baseline: 1.0961x; 1.0961x over previous
//
#include <hip/hip_runtime.h>
#include <hip/hip_bf16.h>
#include <math.h>

using bf16 = __hip_bfloat16;
typedef short bf16x8 __attribute__((ext_vector_type(8)));
typedef float f32x4 __attribute__((ext_vector_type(4)));

#define GAMMA_LOG2 (-0.0014434688536725045f)  // log2(0.999)

union Bf16Bits { bf16 h; unsigned short s; };
union VecU { uint4 q; unsigned short s[8]; };

__device__ inline unsigned short bf16_bits(float z)
{
    Bf16Bits u;
    u.h = __float2bfloat16(z);
    return u.s;
}

__device__ inline unsigned int packbf2(float a, float b)
{
    return (unsigned int)bf16_bits(a) | ((unsigned int)bf16_bits(b) << 16);
}

// async global->LDS, 16 B per lane. LDS dest is wave-uniform base + lane*16.
__device__ __forceinline__ void async_copy16(unsigned short* lds, const bf16* g)
{
    __builtin_amdgcn_global_load_lds(
        (const __attribute__((address_space(1))) unsigned int*)(const void*)g,
        (__attribute__((address_space(3))) unsigned int*)(void*)lds,
        16, 0, 0);
}

// ---------- fused prologue: weight transposes + MLP weight prep + rms(x) ----------
struct PrepArgs {
    const float* src[3];
    bf16* dst[3];
    int R[3];
    int C[3];
    int pfx[4];
};

__global__ void k_prologue(PrepArgs pa,
                           const float* __restrict__ W1, const float* __restrict__ W2,
                           const float* __restrict__ W3, const float* __restrict__ Wz,
                           bf16* __restrict__ Wf,
                           const float* __restrict__ x, bf16* __restrict__ xn)
{
    const int bidg = blockIdx.x;
    if (bidg < 1536) {
        // ---- leg 1: 3 fp32 (R x C) -> bf16 (C x R) transposes ----
        __shared__ float tile[32][33];
        int bid = bidg;
        int seg = 0;
        while (bid >= pa.pfx[seg + 1]) ++seg;
        int local = bid - pa.pfx[seg];
        int R = pa.R[seg], C = pa.C[seg];
        int ctiles = C >> 5;
        int c0 = (local % ctiles) * 32, r0 = (local / ctiles) * 32;
        const float* in = pa.src[seg];
        bf16* out = pa.dst[seg];
        int tx = threadIdx.x & 31, ty = threadIdx.x >> 5;
#pragma unroll
        for (int i = 0; i < 4; ++i) {
            int r = r0 + ty + 8 * i;
            tile[ty + 8 * i][tx] = in[(size_t)r * C + c0 + tx];
        }
        __syncthreads();
#pragma unroll
        for (int i = 0; i < 4; ++i) {
            int cc = c0 + ty + 8 * i, rr = r0 + tx;
            out[(size_t)cc * R + rr] = __float2bfloat16(tile[tx][ty + 8 * i]);
        }
        return;
    }
    if (bidg < 2176) {
        // ---- leg 2: MLP weights -> fragment-major ----
        int g = (bidg - 1536) * 256 + threadIdx.x;   // 163840 threads
        int unit = g >> 15;
        int idx = g & 32767;
        int lane = idx & 63;
        int nj = (idx >> 6) & 7;
        int ks = (idx >> 9) & 15;
        int wc = idx >> 13;
        int lm = lane & 15, lq = lane >> 4;
        int k0 = ks * 32 + lq * 8;
        const float* src;
        int N, o;
        if (unit < 3) {
            src = (unit == 0) ? W1 : (unit == 1) ? W2 : W3;
            N = 512;
            o = wc * 128 + nj * 16 + lm;
        } else {
            src = Wz;
            N = 1024;
            o = (unit - 3) * 512 + wc * 128 + nj * 16 + lm;
        }
        VecU v;
#pragma unroll
        for (int j = 0; j < 8; ++j)
            v.s[j] = bf16_bits(src[(size_t)(k0 + j) * N + o]);
        *(uint4*)(void*)(Wf + (size_t)g * 8) = v.q;
        return;
    }
    // ---- leg 3: x -> srms(x) bf16, one row of 512 per block ----
    {
        int row = bidg - 2176, t = threadIdx.x;
        const float* xr = x + (size_t)row * 512;
        float a = xr[t], b = xr[t + 256];
        float v = a * a + b * b;
#pragma unroll
        for (int m = 32; m >= 1; m >>= 1) v += __shfl_xor(v, m, 64);
        __shared__ float ws[4];
        if ((t & 63) == 0) ws[t >> 6] = v;
        __syncthreads();
        float tot = ws[0] + ws[1] + ws[2] + ws[3];
        float s = 1.f / (sqrtf(tot * (1.f / 512.f)) + 1e-8f);
        bf16* o = xn + (size_t)row * 512;
        o[t] = __float2bfloat16(a * s);
        o[t + 256] = __float2bfloat16(b * s);
    }
}

// ---------- gate + transpose, vectorized (64x64 uint4 tiles) ----------
__global__ void k_gate_transpose(const bf16* __restrict__ ud1t, const bf16* __restrict__ uv,
                                 bf16* __restrict__ out)
{
    __shared__ unsigned short tile[64][65];
    const int b = blockIdx.z;
    const int t = threadIdx.x;
    int c0 = blockIdx.x * 64, t0 = blockIdx.y * 64;
#pragma unroll
    for (int it = 0; it < 2; ++it) {
        int r = it * 32 + (t >> 3), cc = (t & 7) * 8;   // r: channel row, cc: t chunk
        VecU v;
        v.q = *(const uint4*)(const void*)(ud1t + ((size_t)b * 1024 + c0 + r) * 2048 + t0 + cc);
#pragma unroll
        for (int i = 0; i < 8; ++i) tile[r][cc + i] = v.s[i];
    }
    __syncthreads();
#pragma unroll
    for (int it = 0; it < 2; ++it) {
        int tt = it * 32 + (t >> 3), cc = (t & 7) * 8;  // tt: time row, cc: channel chunk
        VecU vu;
        vu.q = *(const uint4*)(const void*)(uv + ((size_t)b * 2048 + t0 + tt) * 2048 + c0 + cc);
        VecU vo;
#pragma unroll
        for (int i = 0; i < 8; ++i) {
            Bf16Bits cv, uu;
            cv.s = tile[cc + i][tt];
            uu.s = vu.s[i];
            vo.s[i] = bf16_bits(__bfloat162float(cv.h) * __bfloat162float(uu.h));
        }
        *(uint4*)(void*)(out + ((size_t)b * 2048 + t0 + tt) * 1024 + c0 + cc) = vo.q;
    }
}

// ---------- fused MLP + uv GEMM (uniform 1024-thread blocks) ----------
// v14: k_mlp (47 us on 64 CUs, rest of chip idle) and k_uv (~38 us) are
// independent given the prologue; fusing hides the MLP under the GEMM.
// Blocks [0,64) = MLP leg (unchanged 16-wave structure). Blocks [64,1088) =
// one 128x128 uv tile each, 16 waves of 32x32 (acc[2][2]); staging is one
// async chunk per thread per K-step, chunk-linear LDS + both-sides swizzle.
// u/v half is block-uniform (gid<512 -> u) so barrier counts stay uniform.
struct SharedFused {
    union {
        struct { unsigned short AB[2][2][4096]; } g;    // 32 KB (also v-stage buffer)
        struct {
            unsigned short X[32][520];
            float sq2[32][33];
            float red[16][32];
            float scale[32];
        } m;                                            // ~40 KB
    };
};

__global__ __launch_bounds__(1024, 2) void k_uv_mlp2(
    const bf16* __restrict__ A, const bf16* __restrict__ Bt,   // xn, Wuvt
    const float* __restrict__ bu, const float* __restrict__ bv,
    const float* __restrict__ Wp, const float* __restrict__ bp,
    const bf16* __restrict__ Wf,
    const float* __restrict__ b1, const float* __restrict__ b2,
    const float* __restrict__ b3, const float* __restrict__ bz,
    bf16* __restrict__ uvb, bf16* __restrict__ vtb, bf16* __restrict__ atb)
{
    __shared__ SharedFused sh;

    const int tid = threadIdx.x, lane = tid & 63, w = tid >> 6;   // w 0..15
    const int lm = lane & 15, lq = lane >> 4;

    if (blockIdx.x < 64) {
        // ================= MLP leg =================
        unsigned short (&X)[32][520] = sh.m.X;
        float (&sq2)[32][33] = sh.m.sq2;
        float (&red)[16][32] = sh.m.red;
        float (&scale)[32] = sh.m.scale;
        const int posBase = blockIdx.x * 32;

        {
            const int r = tid >> 5;            // 0..31
            const int cb = tid & 31;           // 0..31
            const int c0 = cb * 16;
            float vals[16];
            float ssq = 0.f;
            const float fp = (float)(posBase + r);
#pragma unroll
            for (int e = 0; e < 16; ++e) {
                float z = fp * Wp[c0 + e] + bp[c0 + e];
                vals[e] = z;
                ssq += z * z;
            }
            sq2[r][cb] = ssq;
            __syncthreads();
            float tot = 0.f;
#pragma unroll
            for (int i = 0; i < 32; ++i) tot += sq2[r][i];
            float s = 1.f / (sqrtf(tot * (1.f / 512.f)) + 1e-8f);
            unsigned int* xrow = (unsigned int*)&X[r][c0];
#pragma unroll
            for (int e = 0; e < 8; ++e)
                xrow[e] = packbf2(fmaxf(vals[2 * e] * s, 0.f), fmaxf(vals[2 * e + 1] * s, 0.f));
            __syncthreads();
        }

        const int wc = w >> 2, njb = (w & 3) * 2;   // wave's 32-col slice

        auto layer_mm = [&](const bf16* Wu_, f32x4 (&acc)[2][2]) {
            const bf16* base = Wu_ + (size_t)wc * 65536 + (size_t)njb * 512 + (size_t)lane * 8;
            bf16x8 B0[2], B1[2], B2[2], B3[2];
#define LOADB(DST, KS)                                                        \
            DST[0] = *(const bf16x8*)(const void*)(base + (KS) * 4096);       \
            DST[1] = *(const bf16x8*)(const void*)(base + (KS) * 4096 + 512);
#define MMST(BUF, KS) {                                                       \
            bf16x8 af0 = *(const bf16x8*)(const void*)&X[lm][(KS) * 32 + lq * 8]; \
            bf16x8 af1 = *(const bf16x8*)(const void*)&X[16 + lm][(KS) * 32 + lq * 8]; \
            acc[0][0] = __builtin_amdgcn_mfma_f32_16x16x32_bf16(af0, BUF[0], acc[0][0], 0, 0, 0); \
            acc[0][1] = __builtin_amdgcn_mfma_f32_16x16x32_bf16(af0, BUF[1], acc[0][1], 0, 0, 0); \
            acc[1][0] = __builtin_amdgcn_mfma_f32_16x16x32_bf16(af1, BUF[0], acc[1][0], 0, 0, 0); \
            acc[1][1] = __builtin_amdgcn_mfma_f32_16x16x32_bf16(af1, BUF[1], acc[1][1], 0, 0, 0); }
            LOADB(B0, 0)  LOADB(B1, 1)  LOADB(B2, 2)
            LOADB(B3, 3)  MMST(B0, 0)
            LOADB(B0, 4)  MMST(B1, 1)
            LOADB(B1, 5)  MMST(B2, 2)
            LOADB(B2, 6)  MMST(B3, 3)
            LOADB(B3, 7)  MMST(B0, 4)
            LOADB(B0, 8)  MMST(B1, 5)
            LOADB(B1, 9)  MMST(B2, 6)
            LOADB(B2, 10) MMST(B3, 7)
            LOADB(B3, 11) MMST(B0, 8)
            LOADB(B0, 12) MMST(B1, 9)
            LOADB(B1, 13) MMST(B2, 10)
            LOADB(B2, 14) MMST(B3, 11)
            LOADB(B3, 15) MMST(B0, 12)
            MMST(B1, 13)
            MMST(B2, 14)
            MMST(B3, 15)
#undef LOADB
#undef MMST
        };

        const float* bs[3] = {b1, b2, b3};
        for (int l = 0; l < 3; ++l) {
            f32x4 acc[2][2];
#pragma unroll
            for (int mi = 0; mi < 2; ++mi)
#pragma unroll
                for (int i = 0; i < 2; ++i) acc[mi][i] = (f32x4){0.f, 0.f, 0.f, 0.f};
            layer_mm(Wf + (size_t)l * 262144, acc);
#pragma unroll
            for (int mi = 0; mi < 2; ++mi)
#pragma unroll
                for (int nj = 0; nj < 2; ++nj) {
                    float bb = bs[l][w * 32 + nj * 16 + lm];
#pragma unroll
                    for (int r = 0; r < 4; ++r) acc[mi][nj][r] += bb;
                }
            float pr[2][4] = {{0.f, 0.f, 0.f, 0.f}, {0.f, 0.f, 0.f, 0.f}};
#pragma unroll
            for (int mi = 0; mi < 2; ++mi)
#pragma unroll
                for (int nj = 0; nj < 2; ++nj)
#pragma unroll
                    for (int r = 0; r < 4; ++r) pr[mi][r] += acc[mi][nj][r] * acc[mi][nj][r];
#pragma unroll
            for (int m = 1; m < 16; m <<= 1)
#pragma unroll
                for (int mi = 0; mi < 2; ++mi)
#pragma unroll
                    for (int r = 0; r < 4; ++r) pr[mi][r] += __shfl_xor(pr[mi][r], m);
            if (lm == 0)
#pragma unroll
                for (int mi = 0; mi < 2; ++mi)
#pragma unroll
                    for (int r = 0; r < 4; ++r) red[w][mi * 16 + lq * 4 + r] = pr[mi][r];
            __syncthreads();
            if (tid < 32) {
                float tot = 0.f;
#pragma unroll
                for (int wv = 0; wv < 16; ++wv) tot += red[wv][tid];
                scale[tid] = 1.f / (sqrtf(tot * (1.f / 512.f)) + 1e-8f);
            }
            __syncthreads();
#pragma unroll
            for (int mi = 0; mi < 2; ++mi)
#pragma unroll
                for (int nj = 0; nj < 2; ++nj) {
                    int col = w * 32 + nj * 16 + lm;
#pragma unroll
                    for (int r = 0; r < 4; ++r) {
                        int row = mi * 16 + lq * 4 + r;
                        float z = fmaxf(acc[mi][nj][r] * scale[row], 0.f);
                        *(unsigned short*)&X[row][col] = bf16_bits(z);
                    }
                }
            __syncthreads();
        }

#pragma unroll
        for (int h = 0; h < 2; ++h) {
            f32x4 acc[2][2];
#pragma unroll
            for (int mi = 0; mi < 2; ++mi)
#pragma unroll
                for (int i = 0; i < 2; ++i) acc[mi][i] = (f32x4){0.f, 0.f, 0.f, 0.f};
            layer_mm(Wf + (size_t)(3 + h) * 262144, acc);
#pragma unroll
            for (int mi = 0; mi < 2; ++mi)
#pragma unroll
                for (int nj = 0; nj < 2; ++nj) {
                    int col = h * 512 + w * 32 + nj * 16 + lm;
                    float bb = bz[col];
                    int pos0 = posBase + mi * 16 + lq * 4;
                    float zs[4];
#pragma unroll
                    for (int r = 0; r < 4; ++r)
                        zs[r] = (acc[mi][nj][r] + bb) * exp2f((float)(pos0 + r) * GAMMA_LOG2);
                    uint2 o;
                    o.x = packbf2(zs[0], zs[1]);
                    o.y = packbf2(zs[2], zs[3]);
                    *(uint2*)(void*)(atb + (size_t)col * 2048 + pos0) = o;
                }
        }
        return;
    }

    // ================= uv leg: one 128x128 tile, 16 waves =================
    unsigned short (&AB)[2][2][4096] = sh.g.AB;

    const int gid = (int)blockIdx.x - 64;               // 0..1023
    const int wm = (w >> 2) * 32, wn = (w & 3) * 32;    // wave: 32x32 sub-tile
    const long rowBase = (long)(gid & 63) * 128, colBase = (long)(gid >> 6) * 128;

    // staging: 1024 16-B chunks per K-step, exactly one per thread.
    // A chunks: tid<512 (waves 0-7); B chunks: tid>=512 (waves 8-15).
    const int isB = tid >> 9;
    const int ci  = tid & 511;                          // chunk in region
    const int srow = ci >> 2;
    const int sqz  = (ci & 3) ^ ((srow >> 1) & 3);      // swizzled k-chunk
    const bf16* gsrc = (isB ? (Bt + (colBase + srow) * 512)
                            : (A  + (rowBase + srow) * 512)) + sqz * 8;
    unsigned short* ld0 = &AB[0][isB][(w & 7) * 512];   // wave-uniform bases
    unsigned short* ld1 = &AB[1][isB][(w & 7) * 512];

    const int rdA = ((wm + lm) * 4 + (lq ^ ((lm >> 1) & 3))) * 8;
    const int rdB = ((wn + lm) * 4 + (lq ^ ((lm >> 1) & 3))) * 8;

    f32x4 acc[2][2];
    f32x4 zz = {0.f, 0.f, 0.f, 0.f};
#pragma unroll
    for (int i = 0; i < 2; ++i)
#pragma unroll
        for (int j = 0; j < 2; ++j) acc[i][j] = zz;

    async_copy16(ld0, gsrc);
    __syncthreads();

#pragma unroll
    for (int t = 0; t < 16; ++t) {
        const int cur = t & 1;
        if (t < 15)
            async_copy16(cur ? ld0 : ld1, gsrc + (t + 1) * 32);
        bf16x8 af[2], bfr[2];
#pragma unroll
        for (int mi = 0; mi < 2; ++mi)
            af[mi] = *(const bf16x8*)(const void*)&AB[cur][0][rdA + mi * 512];
#pragma unroll
        for (int nj = 0; nj < 2; ++nj)
            bfr[nj] = *(const bf16x8*)(const void*)&AB[cur][1][rdB + nj * 512];
#pragma unroll
        for (int mi = 0; mi < 2; ++mi)
#pragma unroll
            for (int nj = 0; nj < 2; ++nj)
                acc[mi][nj] = __builtin_amdgcn_mfma_f32_16x16x32_bf16(af[mi], bfr[nj], acc[mi][nj], 0, 0, 0);
        if (t < 15) __syncthreads();
    }

    const bool vhalf = colBase >= 1024;   // block-uniform (gid >= 512)
    if (!vhalf) {
#pragma unroll
        for (int mi = 0; mi < 2; ++mi)
#pragma unroll
            for (int nj = 0; nj < 2; ++nj) {
                long col = colBase + wn + nj * 16 + lm;
                float bb = bu[col];
                long row0 = rowBase + wm + mi * 16 + lq * 4;
#pragma unroll
                for (int r = 0; r < 4; ++r) {
                    float z = acc[mi][nj][r] + bb;
                    z = z / (1.f + __expf(-z));
                    uvb[(size_t)(row0 + r) * 2048 + col] = __float2bfloat16(z);
                }
            }
    } else {
        __syncthreads();   // all waves done reading AB
        unsigned short* shv = &AB[0][0][0];   // 128 x 128 shorts, rotation-swizzled
#pragma unroll
        for (int mi = 0; mi < 2; ++mi)
#pragma unroll
            for (int nj = 0; nj < 2; ++nj) {
                int c_local = wn + nj * 16 + lm;
                float bb = bv[colBase - 1024 + c_local];
                int t_local = wm + mi * 16 + lq * 4;
                float zs[4];
#pragma unroll
                for (int r = 0; r < 4; ++r) {
                    float z = acc[mi][nj][r] + bb;
                    zs[r] = z / (1.f + __expf(-z));
                }
                int p = (t_local + 8 * c_local) & 127;
                uint2 o;
                o.x = packbf2(zs[0], zs[1]);
                o.y = packbf2(zs[2], zs[3]);
                *(uint2*)(void*)&shv[c_local * 128 + p] = o;
            }
        __syncthreads();
        const int b   = (int)(rowBase >> 11);
        const int tb0 = (int)(rowBase & 2047);
        const long cb = colBase - 1024;
        const int cl = tid >> 4;    // 0..63
        const int ch = tid & 15;    // 16-B chunk along t
#pragma unroll
        for (int it = 0; it < 2; ++it) {
            int c_local = it * 64 + cl;
            int p = (ch * 8 + 8 * c_local) & 127;
            uint4 q = *(const uint4*)(const void*)&shv[c_local * 128 + p];
            *(uint4*)(void*)(vtb + ((size_t)b * 1024 + cb + c_local) * 2048 + tb0 + ch * 8) = q;
        }
    }
}

// ---------- out projection GEMM v2: async dbuf, 1 barrier/step, 64x128 tile ----------
__global__ __launch_bounds__(256, 4) void k_gemm_out2(
    const bf16* __restrict__ A, const bf16* __restrict__ Bt,
    const float* __restrict__ bias0, const float* __restrict__ addsrc,
    float* __restrict__ outp)
{
    __shared__ unsigned short As[2][64 * 32];    // 8 KB
    __shared__ unsigned short Bs[2][128 * 32];   // 16 KB

    const int tid = threadIdx.x, lane = tid & 63, w = tid >> 6;
    const int lm = lane & 15, lq = lane >> 4;
    const int wm = (w >> 1) * 32, wn = (w & 1) * 64;   // wave: 32 rows x 64 cols
    const long rowBase = (long)blockIdx.x * 64, colBase = (long)blockIdx.y * 128;

    const int srow = tid >> 2;                        // 0..63
    const int sqz  = (tid & 3) ^ ((srow >> 1) & 3);   // swizzled k-chunk
    const bf16* gA  = A  + (rowBase + srow) * 1024 + sqz * 8;
    const bf16* gB  = Bt + (colBase + srow) * 1024 + sqz * 8;
    const bf16* gB2 = gB + (size_t)64 * 1024;
    const int lsA = w * 512;
    const int lsB0 = w * 512, lsB1 = 2048 + w * 512;

    const int rdA = ((wm + lm) * 4 + (lq ^ ((lm >> 1) & 3))) * 8;
    const int rdB = ((wn + lm) * 4 + (lq ^ ((lm >> 1) & 3))) * 8;

    f32x4 acc[2][4];
    f32x4 zz = {0.f, 0.f, 0.f, 0.f};
#pragma unroll
    for (int i = 0; i < 2; ++i)
#pragma unroll
        for (int j = 0; j < 4; ++j) acc[i][j] = zz;

    async_copy16(&As[0][lsA], gA);
    async_copy16(&Bs[0][lsB0], gB);
    async_copy16(&Bs[0][lsB1], gB2);
    __syncthreads();

#pragma unroll
    for (int t = 0; t < 32; ++t) {
        const int cur = t & 1;
        if (t < 31) {
            const int kk = (t + 1) * 32;
            async_copy16(&As[cur ^ 1][lsA], gA + kk);
            async_copy16(&Bs[cur ^ 1][lsB0], gB + kk);
            async_copy16(&Bs[cur ^ 1][lsB1], gB2 + kk);
        }
        bf16x8 af[2], bfr[4];
#pragma unroll
        for (int mi = 0; mi < 2; ++mi)
            af[mi] = *(const bf16x8*)(const void*)&As[cur][rdA + mi * 512];
#pragma unroll
        for (int nj = 0; nj < 4; ++nj)
            bfr[nj] = *(const bf16x8*)(const void*)&Bs[cur][rdB + nj * 512];
#pragma unroll
        for (int mi = 0; mi < 2; ++mi)
#pragma unroll
            for (int nj = 0; nj < 4; ++nj)
                acc[mi][nj] = __builtin_amdgcn_mfma_f32_16x16x32_bf16(af[mi], bfr[nj], acc[mi][nj], 0, 0, 0);
        if (t < 31) __syncthreads();
    }

#pragma unroll
    for (int mi = 0; mi < 2; ++mi)
#pragma unroll
        for (int nj = 0; nj < 4; ++nj) {
            long col = colBase + wn + nj * 16 + lm;
            float bb = bias0[col];
#pragma unroll
            for (int r = 0; r < 4; ++r) {
                long row = rowBase + wm + mi * 16 + lq * 4 + r;
                size_t off = (size_t)row * 512 + col;
                outp[off] = acc[mi][nj][r] + bb + addsrc[off];
            }
        }
}

// ---------- Toeplitz-MFMA depthwise causal conv (v4, diagonal-reuse) ----------
__global__ __launch_bounds__(256, 4) void k_conv_mfma(
    const bf16* __restrict__ vt, const bf16* __restrict__ at, bf16* __restrict__ ud1t)
{
    __shared__ unsigned short ash2[2][2068];  // reversed filter, 2 shifted copies
    __shared__ unsigned short vsh[4][3072];   // per-batch v, stride 24 per 16-elem tile

    const int tid = threadIdx.x, lane = tid & 63, w = tid >> 6;
    const int c = blockIdx.x;

    {
        const unsigned short* asrc = (const unsigned short*)(at + (size_t)c * 2048);
        for (int i = tid; i < 2068; i += 256) {
#pragma unroll
            for (int k = 0; k < 2; ++k) {
                int src = 2047 - i - k;
                ash2[k][i] = (src >= 0) ? asrc[src] : (unsigned short)0;
            }
        }
    }
    {
        const bf16* vsrc = vt + ((size_t)w * 1024 + c) * 2048;
#pragma unroll
        for (int q = 0; q < 4; ++q) {
            int li = q * 64 + lane;
            int tile = li >> 1, hf = li & 1;
            *(uint4*)(void*)&vsh[w][tile * 24 + hf * 8] =
                *(const uint4*)(const void*)(vsrc + li * 8);
        }
    }
    __syncthreads();

    const int lm = lane & 15, lq = lane >> 4;
    const int h = lq >> 1, p0 = (lq & 1) * 8;
    const int kcopy = (lm + 1) & 1;
    const int base = 31 - 16 * h - lm + p0 - kcopy;
    const unsigned int* aw = (const unsigned int*)(void*)&ash2[kcopy][0] + (base >> 1);
    const unsigned short* vw = &vsh[w][0];

    f32x4 acc[8];
    f32x4 zz = {0.f, 0.f, 0.f, 0.f};
#pragma unroll
    for (int i = 0; i < 8; ++i) acc[i] = zz;
    const bf16x8 zfrag = (bf16x8)(short)0;

    for (int d2 = 0; d2 < 16; d2 += 2) {
        bf16x8 vf[8];
        const int tb = lm - d2 - h;
        {
            int T = tb > 0 ? tb : 0;
            bf16x8 f = *(const bf16x8*)(const void*)(vw + T * 24 + p0);
            vf[0] = (tb < 0) ? zfrag : f;
        }
#pragma unroll
        for (int dl = 1; dl < 8; ++dl)
            vf[dl] = *(const bf16x8*)(const void*)(vw + (dl * 16 + tb) * 24 + p0);

#pragma unroll
        for (int dt = 0; dt < 8; ++dt) {
            const int m16 = (63 - ((dt * 16 + d2) >> 1)) * 16;
            union { unsigned int u[4]; bf16x8 v; } af;
            af.u[0] = aw[m16 + 0];
            af.u[1] = aw[m16 + 1];
            af.u[2] = aw[m16 + 2];
            af.u[3] = aw[m16 + 3];
#pragma unroll
            for (int dl = 0; dl < 8 - dt; ++dl)
                acc[dt + dl] = __builtin_amdgcn_mfma_f32_16x16x32_bf16(af.v, vf[dl], acc[dt + dl], 0, 0, 0);
        }
    }

    __syncthreads();
    float* stg = (float*)(void*)((char*)(void*)&ash2[0][0] + w * 1024);
    bf16* dst = ud1t + ((size_t)w * 1024 + c) * 2048;
#pragma unroll
    for (int jg = 0; jg < 8; ++jg) {
        *(f32x4*)(void*)&stg[lm * 16 + lq * 4] = acc[jg];
        f32x4 vv = *(const f32x4*)(const void*)&stg[lane * 4];
        uint2 o;
        o.x = packbf2(vv.x, vv.y);
        o.y = packbf2(vv.z, vv.w);
        *(uint2*)(void*)(dst + jg * 256 + lane * 4) = o;
    }
}

extern "C" void kernel_launch(void* const* d_in, const int* in_sizes, int n_in,
                              void* d_out, int out_size, void* d_ws, size_t ws_size,
                              hipStream_t stream)
{
    const float* x  = (const float*)d_in[0];
    const float* Wu = (const float*)d_in[1];
    const float* bu = (const float*)d_in[2];
    const float* Wv = (const float*)d_in[3];
    const float* bv = (const float*)d_in[4];
    const float* Wo = (const float*)d_in[5];
    const float* bo = (const float*)d_in[6];
    const float* Wp = (const float*)d_in[7];
    const float* bp = (const float*)d_in[8];
    const float* W1 = (const float*)d_in[9];
    const float* b1 = (const float*)d_in[10];
    const float* W2 = (const float*)d_in[11];
    const float* b2 = (const float*)d_in[12];
    const float* W3 = (const float*)d_in[13];
    const float* b3 = (const float*)d_in[14];
    const float* Wz = (const float*)d_in[15];
    const float* bz = (const float*)d_in[16];

    char* p = (char*)d_ws;
    auto carve = [&](size_t bytes) { void* q = (void*)p; p += (bytes + 255) & ~(size_t)255; return q; };
    bf16*  xn   = (bf16*)carve((size_t)8192 * 512 * 2);
    bf16*  Wuvt = (bf16*)carve((size_t)2048 * 512 * 2);
    bf16*  Wot  = (bf16*)carve((size_t)512 * 1024 * 2);
    bf16*  Wf   = (bf16*)carve((size_t)5 * 262144 * 2);       // fragment-major MLP weights
    bf16*  uvb  = (bf16*)carve((size_t)8192 * 2048 * 2);      // u silu output (t, c); v-half unused
    bf16*  ud1  = (bf16*)carve((size_t)8192 * 1024 * 2);      // u * conv, (t, c)
    bf16*  vtb  = (bf16*)carve((size_t)4 * 1024 * 2048 * 2);  // v (b,c,t)
    bf16*  atb  = (bf16*)carve((size_t)1024 * 2048 * 2);      // a (c,k)
    bf16*  ud1t = (bf16*)carve((size_t)4 * 1024 * 2048 * 2);  // conv result (b,c,t)

    // fused prologue: weight transposes + MLP weight prep + rms(x)
    PrepArgs pa;
    const float* srcs[3] = {Wu, Wv, Wo};
    bf16* dsts[3] = {Wuvt, Wuvt + (size_t)1024 * 512, Wot};
    int Rs[3] = {512, 512, 1024};
    int Cs[3] = {1024, 1024, 512};
    int acc_t = 0;
    for (int i = 0; i < 3; ++i) {
        pa.src[i] = srcs[i]; pa.dst[i] = dsts[i]; pa.R[i] = Rs[i]; pa.C[i] = Cs[i];
        pa.pfx[i] = acc_t;
        acc_t += (Rs[i] / 32) * (Cs[i] / 32);
    }
    pa.pfx[3] = acc_t;  // 1536
    k_prologue<<<1536 + 640 + 8192, 256, 0, stream>>>(pa, W1, W2, W3, Wz, Wf, x, xn);

    // fused: positional MLP (64 blocks) + uv GEMM (1024 blocks), 1024 threads
    k_uv_mlp2<<<1088, 1024, 0, stream>>>(xn, Wuvt, bu, bv, Wp, bp,
                                         Wf, b1, b2, b3, bz, uvb, vtb, atb);

    // causal depthwise conv via Toeplitz-MFMA (block = channel x 4 batches)
    k_conv_mfma<<<dim3(1024), 256, 0, stream>>>(vtb, atb, ud1t);

    // gate by u and transpose back to (t, c) — vectorized
    k_gate_transpose<<<dim3(16, 32, 4), 256, 0, stream>>>(ud1t, uvb, ud1);

    // y = ud1 @ Wo + bo + x  (async dbuf structure, 512 blocks)
    k_gemm_out2<<<dim3(128, 4), 256, 0, stream>>>(ud1, Wot, bo, x, (float*)d_out);
}

// Round 14
// 206.681 us; speedup vs baseline: 1.1186x; 1.0206x over previous
//
#include <hip/hip_runtime.h>
#include <hip/hip_bf16.h>
#include <math.h>

using bf16 = __hip_bfloat16;
typedef short bf16x8 __attribute__((ext_vector_type(8)));
typedef float f32x4 __attribute__((ext_vector_type(4)));

#define GAMMA_LOG2 (-0.0014434688536725045f)  // log2(0.999)

union Bf16Bits { bf16 h; unsigned short s; };
union VecU { uint4 q; unsigned short s[8]; };

__device__ inline unsigned short bf16_bits(float z)
{
    Bf16Bits u;
    u.h = __float2bfloat16(z);
    return u.s;
}

__device__ inline unsigned int packbf2(float a, float b)
{
    return (unsigned int)bf16_bits(a) | ((unsigned int)bf16_bits(b) << 16);
}

// async global->LDS, 16 B per lane. LDS dest is wave-uniform base + lane*16.
__device__ __forceinline__ void async_copy16(unsigned short* lds, const bf16* g)
{
    __builtin_amdgcn_global_load_lds(
        (const __attribute__((address_space(1))) unsigned int*)(const void*)g,
        (__attribute__((address_space(3))) unsigned int*)(void*)lds,
        16, 0, 0);
}

// ---------- fused prologue: weight transposes + MLP weight prep + rms(x) ----------
struct PrepArgs {
    const float* src[3];
    bf16* dst[3];
    int R[3];
    int C[3];
    int pfx[4];
};

__global__ void k_prologue(PrepArgs pa,
                           const float* __restrict__ W1, const float* __restrict__ W2,
                           const float* __restrict__ W3, const float* __restrict__ Wz,
                           bf16* __restrict__ Wf,
                           const float* __restrict__ x, bf16* __restrict__ xn)
{
    const int bidg = blockIdx.x;
    if (bidg < 1536) {
        // ---- leg 1: 3 fp32 (R x C) -> bf16 (C x R) transposes ----
        __shared__ float tile[32][33];
        int bid = bidg;
        int seg = 0;
        while (bid >= pa.pfx[seg + 1]) ++seg;
        int local = bid - pa.pfx[seg];
        int R = pa.R[seg], C = pa.C[seg];
        int ctiles = C >> 5;
        int c0 = (local % ctiles) * 32, r0 = (local / ctiles) * 32;
        const float* in = pa.src[seg];
        bf16* out = pa.dst[seg];
        int tx = threadIdx.x & 31, ty = threadIdx.x >> 5;
#pragma unroll
        for (int i = 0; i < 4; ++i) {
            int r = r0 + ty + 8 * i;
            tile[ty + 8 * i][tx] = in[(size_t)r * C + c0 + tx];
        }
        __syncthreads();
#pragma unroll
        for (int i = 0; i < 4; ++i) {
            int cc = c0 + ty + 8 * i, rr = r0 + tx;
            out[(size_t)cc * R + rr] = __float2bfloat16(tile[tx][ty + 8 * i]);
        }
        return;
    }
    if (bidg < 2176) {
        // ---- leg 2: MLP weights -> fragment-major ----
        int g = (bidg - 1536) * 256 + threadIdx.x;   // 163840 threads
        int unit = g >> 15;
        int idx = g & 32767;
        int lane = idx & 63;
        int nj = (idx >> 6) & 7;
        int ks = (idx >> 9) & 15;
        int wc = idx >> 13;
        int lm = lane & 15, lq = lane >> 4;
        int k0 = ks * 32 + lq * 8;
        const float* src;
        int N, o;
        if (unit < 3) {
            src = (unit == 0) ? W1 : (unit == 1) ? W2 : W3;
            N = 512;
            o = wc * 128 + nj * 16 + lm;
        } else {
            src = Wz;
            N = 1024;
            o = (unit - 3) * 512 + wc * 128 + nj * 16 + lm;
        }
        VecU v;
#pragma unroll
        for (int j = 0; j < 8; ++j)
            v.s[j] = bf16_bits(src[(size_t)(k0 + j) * N + o]);
        *(uint4*)(void*)(Wf + (size_t)g * 8) = v.q;
        return;
    }
    // ---- leg 3: x -> srms(x) bf16, one row of 512 per block ----
    {
        int row = bidg - 2176, t = threadIdx.x;
        const float* xr = x + (size_t)row * 512;
        float a = xr[t], b = xr[t + 256];
        float v = a * a + b * b;
#pragma unroll
        for (int m = 32; m >= 1; m >>= 1) v += __shfl_xor(v, m, 64);
        __shared__ float ws[4];
        if ((t & 63) == 0) ws[t >> 6] = v;
        __syncthreads();
        float tot = ws[0] + ws[1] + ws[2] + ws[3];
        float s = 1.f / (sqrtf(tot * (1.f / 512.f)) + 1e-8f);
        bf16* o = xn + (size_t)row * 512;
        o[t] = __float2bfloat16(a * s);
        o[t + 256] = __float2bfloat16(b * s);
    }
}

// ---------- gate + transpose, vectorized (64x64 uint4 tiles) ----------
__global__ void k_gate_transpose(const bf16* __restrict__ ud1t, const bf16* __restrict__ uv,
                                 bf16* __restrict__ out)
{
    __shared__ unsigned short tile[64][65];
    const int b = blockIdx.z;
    const int t = threadIdx.x;
    int c0 = blockIdx.x * 64, t0 = blockIdx.y * 64;
#pragma unroll
    for (int it = 0; it < 2; ++it) {
        int r = it * 32 + (t >> 3), cc = (t & 7) * 8;   // r: channel row, cc: t chunk
        VecU v;
        v.q = *(const uint4*)(const void*)(ud1t + ((size_t)b * 1024 + c0 + r) * 2048 + t0 + cc);
#pragma unroll
        for (int i = 0; i < 8; ++i) tile[r][cc + i] = v.s[i];
    }
    __syncthreads();
#pragma unroll
    for (int it = 0; it < 2; ++it) {
        int tt = it * 32 + (t >> 3), cc = (t & 7) * 8;  // tt: time row, cc: channel chunk
        VecU vu;
        vu.q = *(const uint4*)(const void*)(uv + ((size_t)b * 2048 + t0 + tt) * 2048 + c0 + cc);
        VecU vo;
#pragma unroll
        for (int i = 0; i < 8; ++i) {
            Bf16Bits cv, uu;
            cv.s = tile[cc + i][tt];
            uu.s = vu.s[i];
            vo.s[i] = bf16_bits(__bfloat162float(cv.h) * __bfloat162float(uu.h));
        }
        *(uint4*)(void*)(out + ((size_t)b * 2048 + t0 + tt) * 1024 + c0 + cc) = vo.q;
    }
}

// ---------- fused MLP + uv GEMM (uniform 1024-thread blocks) ----------
// v15: the MLP leg's Wf prefetch was defeated twice by the compiler (R10:
// scratch ring; R12: named ring load-sunk next to use, VGPR=36). Fix is the
// T4 counted-vmcnt pattern in inline asm: global_load_dwordx4 issued as
// opaque asm (cannot be sunk), explicit s_waitcnt vmcnt(6..0) +
// sched_barrier(0) (rule #18) before each MFMA group. 8 loads (4 K-steps)
// stay in flight permanently. launch_bounds(1024,1): ring costs real VGPRs.
struct SharedFused {
    union {
        struct { unsigned short AB[2][2][4096]; } g;    // 32 KB (also v-stage buffer)
        struct {
            unsigned short X[32][520];
            float sq2[32][33];
            float red[16][32];
            float scale[32];
        } m;                                            // ~40 KB
    };
};

__global__ __launch_bounds__(1024, 1) void k_uv_mlp2(
    const bf16* __restrict__ A, const bf16* __restrict__ Bt,   // xn, Wuvt
    const float* __restrict__ bu, const float* __restrict__ bv,
    const float* __restrict__ Wp, const float* __restrict__ bp,
    const bf16* __restrict__ Wf,
    const float* __restrict__ b1, const float* __restrict__ b2,
    const float* __restrict__ b3, const float* __restrict__ bz,
    bf16* __restrict__ uvb, bf16* __restrict__ vtb, bf16* __restrict__ atb)
{
    __shared__ SharedFused sh;

    const int tid = threadIdx.x, lane = tid & 63, w = tid >> 6;   // w 0..15
    const int lm = lane & 15, lq = lane >> 4;

    if (blockIdx.x < 64) {
        // ================= MLP leg =================
        unsigned short (&X)[32][520] = sh.m.X;
        float (&sq2)[32][33] = sh.m.sq2;
        float (&red)[16][32] = sh.m.red;
        float (&scale)[32] = sh.m.scale;
        const int posBase = blockIdx.x * 32;

        {
            const int r = tid >> 5;            // 0..31
            const int cb = tid & 31;           // 0..31
            const int c0 = cb * 16;
            float vals[16];
            float ssq = 0.f;
            const float fp = (float)(posBase + r);
#pragma unroll
            for (int e = 0; e < 16; ++e) {
                float z = fp * Wp[c0 + e] + bp[c0 + e];
                vals[e] = z;
                ssq += z * z;
            }
            sq2[r][cb] = ssq;
            __syncthreads();
            float tot = 0.f;
#pragma unroll
            for (int i = 0; i < 32; ++i) tot += sq2[r][i];
            float s = 1.f / (sqrtf(tot * (1.f / 512.f)) + 1e-8f);
            unsigned int* xrow = (unsigned int*)&X[r][c0];
#pragma unroll
            for (int e = 0; e < 8; ++e)
                xrow[e] = packbf2(fmaxf(vals[2 * e] * s, 0.f), fmaxf(vals[2 * e + 1] * s, 0.f));
            __syncthreads();
        }

        const int wc = w >> 2, njb = (w & 3) * 2;   // wave's 32-col slice

        // one 512-K GEMM pass; asm-pinned loads + counted vmcnt (4-step depth)
        auto layer_mm = [&](const bf16* Wu_, f32x4 (&acc)[2][2]) {
            const bf16* base = Wu_ + (size_t)wc * 65536 + (size_t)njb * 512 + (size_t)lane * 8;
            bf16x8 B00, B01, B10, B11, B20, B21, B30, B31;
#define GL2(D0, D1, KS)                                                       \
            asm volatile("global_load_dwordx4 %0, %2, off\n\t"                \
                         "global_load_dwordx4 %1, %2, off offset:1024"        \
                         : "=&v"(D0), "=&v"(D1)                               \
                         : "v"(base + (size_t)(KS) * 4096) : "memory");
#define WAITV(N)                                                              \
            asm volatile("s_waitcnt vmcnt(" #N ")" ::: "memory");             \
            __builtin_amdgcn_sched_barrier(0);
#define MMST(BA, BB, KS) {                                                    \
            bf16x8 af0 = *(const bf16x8*)(const void*)&X[lm][(KS) * 32 + lq * 8]; \
            bf16x8 af1 = *(const bf16x8*)(const void*)&X[16 + lm][(KS) * 32 + lq * 8]; \
            acc[0][0] = __builtin_amdgcn_mfma_f32_16x16x32_bf16(af0, BA, acc[0][0], 0, 0, 0); \
            acc[0][1] = __builtin_amdgcn_mfma_f32_16x16x32_bf16(af0, BB, acc[0][1], 0, 0, 0); \
            acc[1][0] = __builtin_amdgcn_mfma_f32_16x16x32_bf16(af1, BA, acc[1][0], 0, 0, 0); \
            acc[1][1] = __builtin_amdgcn_mfma_f32_16x16x32_bf16(af1, BB, acc[1][1], 0, 0, 0); }
            GL2(B00, B01, 0) GL2(B10, B11, 1) GL2(B20, B21, 2) GL2(B30, B31, 3)
            WAITV(6) MMST(B00, B01, 0)  GL2(B00, B01, 4)
            WAITV(6) MMST(B10, B11, 1)  GL2(B10, B11, 5)
            WAITV(6) MMST(B20, B21, 2)  GL2(B20, B21, 6)
            WAITV(6) MMST(B30, B31, 3)  GL2(B30, B31, 7)
            WAITV(6) MMST(B00, B01, 4)  GL2(B00, B01, 8)
            WAITV(6) MMST(B10, B11, 5)  GL2(B10, B11, 9)
            WAITV(6) MMST(B20, B21, 6)  GL2(B20, B21, 10)
            WAITV(6) MMST(B30, B31, 7)  GL2(B30, B31, 11)
            WAITV(6) MMST(B00, B01, 8)  GL2(B00, B01, 12)
            WAITV(6) MMST(B10, B11, 9)  GL2(B10, B11, 13)
            WAITV(6) MMST(B20, B21, 10) GL2(B20, B21, 14)
            WAITV(6) MMST(B30, B31, 11) GL2(B30, B31, 15)
            WAITV(6) MMST(B00, B01, 12)
            WAITV(4) MMST(B10, B11, 13)
            WAITV(2) MMST(B20, B21, 14)
            WAITV(0) MMST(B30, B31, 15)
#undef GL2
#undef WAITV
#undef MMST
        };

        const float* bs[3] = {b1, b2, b3};
        for (int l = 0; l < 3; ++l) {
            f32x4 acc[2][2];
#pragma unroll
            for (int mi = 0; mi < 2; ++mi)
#pragma unroll
                for (int i = 0; i < 2; ++i) acc[mi][i] = (f32x4){0.f, 0.f, 0.f, 0.f};
            layer_mm(Wf + (size_t)l * 262144, acc);
#pragma unroll
            for (int mi = 0; mi < 2; ++mi)
#pragma unroll
                for (int nj = 0; nj < 2; ++nj) {
                    float bb = bs[l][w * 32 + nj * 16 + lm];
#pragma unroll
                    for (int r = 0; r < 4; ++r) acc[mi][nj][r] += bb;
                }
            float pr[2][4] = {{0.f, 0.f, 0.f, 0.f}, {0.f, 0.f, 0.f, 0.f}};
#pragma unroll
            for (int mi = 0; mi < 2; ++mi)
#pragma unroll
                for (int nj = 0; nj < 2; ++nj)
#pragma unroll
                    for (int r = 0; r < 4; ++r) pr[mi][r] += acc[mi][nj][r] * acc[mi][nj][r];
#pragma unroll
            for (int m = 1; m < 16; m <<= 1)
#pragma unroll
                for (int mi = 0; mi < 2; ++mi)
#pragma unroll
                    for (int r = 0; r < 4; ++r) pr[mi][r] += __shfl_xor(pr[mi][r], m);
            if (lm == 0)
#pragma unroll
                for (int mi = 0; mi < 2; ++mi)
#pragma unroll
                    for (int r = 0; r < 4; ++r) red[w][mi * 16 + lq * 4 + r] = pr[mi][r];
            __syncthreads();
            if (tid < 32) {
                float tot = 0.f;
#pragma unroll
                for (int wv = 0; wv < 16; ++wv) tot += red[wv][tid];
                scale[tid] = 1.f / (sqrtf(tot * (1.f / 512.f)) + 1e-8f);
            }
            __syncthreads();
#pragma unroll
            for (int mi = 0; mi < 2; ++mi)
#pragma unroll
                for (int nj = 0; nj < 2; ++nj) {
                    int col = w * 32 + nj * 16 + lm;
#pragma unroll
                    for (int r = 0; r < 4; ++r) {
                        int row = mi * 16 + lq * 4 + r;
                        float z = fmaxf(acc[mi][nj][r] * scale[row], 0.f);
                        *(unsigned short*)&X[row][col] = bf16_bits(z);
                    }
                }
            __syncthreads();
        }

#pragma unroll
        for (int h = 0; h < 2; ++h) {
            f32x4 acc[2][2];
#pragma unroll
            for (int mi = 0; mi < 2; ++mi)
#pragma unroll
                for (int i = 0; i < 2; ++i) acc[mi][i] = (f32x4){0.f, 0.f, 0.f, 0.f};
            layer_mm(Wf + (size_t)(3 + h) * 262144, acc);
#pragma unroll
            for (int mi = 0; mi < 2; ++mi)
#pragma unroll
                for (int nj = 0; nj < 2; ++nj) {
                    int col = h * 512 + w * 32 + nj * 16 + lm;
                    float bb = bz[col];
                    int pos0 = posBase + mi * 16 + lq * 4;
                    float zs[4];
#pragma unroll
                    for (int r = 0; r < 4; ++r)
                        zs[r] = (acc[mi][nj][r] + bb) * exp2f((float)(pos0 + r) * GAMMA_LOG2);
                    uint2 o;
                    o.x = packbf2(zs[0], zs[1]);
                    o.y = packbf2(zs[2], zs[3]);
                    *(uint2*)(void*)(atb + (size_t)col * 2048 + pos0) = o;
                }
        }
        return;
    }

    // ================= uv leg: one 128x128 tile, 16 waves =================
    unsigned short (&AB)[2][2][4096] = sh.g.AB;

    const int gid = (int)blockIdx.x - 64;               // 0..1023
    const int wm = (w >> 2) * 32, wn = (w & 3) * 32;    // wave: 32x32 sub-tile
    const long rowBase = (long)(gid & 63) * 128, colBase = (long)(gid >> 6) * 128;

    // staging: 1024 16-B chunks per K-step, exactly one per thread.
    // A chunks: tid<512 (waves 0-7); B chunks: tid>=512 (waves 8-15).
    const int isB = tid >> 9;
    const int ci  = tid & 511;                          // chunk in region
    const int srow = ci >> 2;
    const int sqz  = (ci & 3) ^ ((srow >> 1) & 3);      // swizzled k-chunk
    const bf16* gsrc = (isB ? (Bt + (colBase + srow) * 512)
                            : (A  + (rowBase + srow) * 512)) + sqz * 8;
    unsigned short* ld0 = &AB[0][isB][(w & 7) * 512];   // wave-uniform bases
    unsigned short* ld1 = &AB[1][isB][(w & 7) * 512];

    const int rdA = ((wm + lm) * 4 + (lq ^ ((lm >> 1) & 3))) * 8;
    const int rdB = ((wn + lm) * 4 + (lq ^ ((lm >> 1) & 3))) * 8;

    f32x4 acc[2][2];
    f32x4 zz = {0.f, 0.f, 0.f, 0.f};
#pragma unroll
    for (int i = 0; i < 2; ++i)
#pragma unroll
        for (int j = 0; j < 2; ++j) acc[i][j] = zz;

    async_copy16(ld0, gsrc);
    __syncthreads();

#pragma unroll
    for (int t = 0; t < 16; ++t) {
        const int cur = t & 1;
        if (t < 15)
            async_copy16(cur ? ld0 : ld1, gsrc + (t + 1) * 32);
        bf16x8 af[2], bfr[2];
#pragma unroll
        for (int mi = 0; mi < 2; ++mi)
            af[mi] = *(const bf16x8*)(const void*)&AB[cur][0][rdA + mi * 512];
#pragma unroll
        for (int nj = 0; nj < 2; ++nj)
            bfr[nj] = *(const bf16x8*)(const void*)&AB[cur][1][rdB + nj * 512];
#pragma unroll
        for (int mi = 0; mi < 2; ++mi)
#pragma unroll
            for (int nj = 0; nj < 2; ++nj)
                acc[mi][nj] = __builtin_amdgcn_mfma_f32_16x16x32_bf16(af[mi], bfr[nj], acc[mi][nj], 0, 0, 0);
        if (t < 15) __syncthreads();
    }

    const bool vhalf = colBase >= 1024;   // block-uniform (gid >= 512)
    if (!vhalf) {
#pragma unroll
        for (int mi = 0; mi < 2; ++mi)
#pragma unroll
            for (int nj = 0; nj < 2; ++nj) {
                long col = colBase + wn + nj * 16 + lm;
                float bb = bu[col];
                long row0 = rowBase + wm + mi * 16 + lq * 4;
#pragma unroll
                for (int r = 0; r < 4; ++r) {
                    float z = acc[mi][nj][r] + bb;
                    z = z / (1.f + __expf(-z));
                    uvb[(size_t)(row0 + r) * 2048 + col] = __float2bfloat16(z);
                }
            }
    } else {
        __syncthreads();   // all waves done reading AB
        unsigned short* shv = &AB[0][0][0];   // 128 x 128 shorts, rotation-swizzled
#pragma unroll
        for (int mi = 0; mi < 2; ++mi)
#pragma unroll
            for (int nj = 0; nj < 2; ++nj) {
                int c_local = wn + nj * 16 + lm;
                float bb = bv[colBase - 1024 + c_local];
                int t_local = wm + mi * 16 + lq * 4;
                float zs[4];
#pragma unroll
                for (int r = 0; r < 4; ++r) {
                    float z = acc[mi][nj][r] + bb;
                    zs[r] = z / (1.f + __expf(-z));
                }
                int p = (t_local + 8 * c_local) & 127;
                uint2 o;
                o.x = packbf2(zs[0], zs[1]);
                o.y = packbf2(zs[2], zs[3]);
                *(uint2*)(void*)&shv[c_local * 128 + p] = o;
            }
        __syncthreads();
        const int b   = (int)(rowBase >> 11);
        const int tb0 = (int)(rowBase & 2047);
        const long cb = colBase - 1024;
        const int cl = tid >> 4;    // 0..63
        const int ch = tid & 15;    // 16-B chunk along t
#pragma unroll
        for (int it = 0; it < 2; ++it) {
            int c_local = it * 64 + cl;
            int p = (ch * 8 + 8 * c_local) & 127;
            uint4 q = *(const uint4*)(const void*)&shv[c_local * 128 + p];
            *(uint4*)(void*)(vtb + ((size_t)b * 1024 + cb + c_local) * 2048 + tb0 + ch * 8) = q;
        }
    }
}

// ---------- out projection GEMM v2: async dbuf, 1 barrier/step, 64x128 tile ----------
__global__ __launch_bounds__(256, 4) void k_gemm_out2(
    const bf16* __restrict__ A, const bf16* __restrict__ Bt,
    const float* __restrict__ bias0, const float* __restrict__ addsrc,
    float* __restrict__ outp)
{
    __shared__ unsigned short As[2][64 * 32];    // 8 KB
    __shared__ unsigned short Bs[2][128 * 32];   // 16 KB

    const int tid = threadIdx.x, lane = tid & 63, w = tid >> 6;
    const int lm = lane & 15, lq = lane >> 4;
    const int wm = (w >> 1) * 32, wn = (w & 1) * 64;   // wave: 32 rows x 64 cols
    const long rowBase = (long)blockIdx.x * 64, colBase = (long)blockIdx.y * 128;

    const int srow = tid >> 2;                        // 0..63
    const int sqz  = (tid & 3) ^ ((srow >> 1) & 3);   // swizzled k-chunk
    const bf16* gA  = A  + (rowBase + srow) * 1024 + sqz * 8;
    const bf16* gB  = Bt + (colBase + srow) * 1024 + sqz * 8;
    const bf16* gB2 = gB + (size_t)64 * 1024;
    const int lsA = w * 512;
    const int lsB0 = w * 512, lsB1 = 2048 + w * 512;

    const int rdA = ((wm + lm) * 4 + (lq ^ ((lm >> 1) & 3))) * 8;
    const int rdB = ((wn + lm) * 4 + (lq ^ ((lm >> 1) & 3))) * 8;

    f32x4 acc[2][4];
    f32x4 zz = {0.f, 0.f, 0.f, 0.f};
#pragma unroll
    for (int i = 0; i < 2; ++i)
#pragma unroll
        for (int j = 0; j < 4; ++j) acc[i][j] = zz;

    async_copy16(&As[0][lsA], gA);
    async_copy16(&Bs[0][lsB0], gB);
    async_copy16(&Bs[0][lsB1], gB2);
    __syncthreads();

#pragma unroll
    for (int t = 0; t < 32; ++t) {
        const int cur = t & 1;
        if (t < 31) {
            const int kk = (t + 1) * 32;
            async_copy16(&As[cur ^ 1][lsA], gA + kk);
            async_copy16(&Bs[cur ^ 1][lsB0], gB + kk);
            async_copy16(&Bs[cur ^ 1][lsB1], gB2 + kk);
        }
        bf16x8 af[2], bfr[4];
#pragma unroll
        for (int mi = 0; mi < 2; ++mi)
            af[mi] = *(const bf16x8*)(const void*)&As[cur][rdA + mi * 512];
#pragma unroll
        for (int nj = 0; nj < 4; ++nj)
            bfr[nj] = *(const bf16x8*)(const void*)&Bs[cur][rdB + nj * 512];
#pragma unroll
        for (int mi = 0; mi < 2; ++mi)
#pragma unroll
            for (int nj = 0; nj < 4; ++nj)
                acc[mi][nj] = __builtin_amdgcn_mfma_f32_16x16x32_bf16(af[mi], bfr[nj], acc[mi][nj], 0, 0, 0);
        if (t < 31) __syncthreads();
    }

#pragma unroll
    for (int mi = 0; mi < 2; ++mi)
#pragma unroll
        for (int nj = 0; nj < 4; ++nj) {
            long col = colBase + wn + nj * 16 + lm;
            float bb = bias0[col];
#pragma unroll
            for (int r = 0; r < 4; ++r) {
                long row = rowBase + wm + mi * 16 + lq * 4 + r;
                size_t off = (size_t)row * 512 + col;
                outp[off] = acc[mi][nj][r] + bb + addsrc[off];
            }
        }
}

// ---------- Toeplitz-MFMA depthwise causal conv (v4, diagonal-reuse) ----------
__global__ __launch_bounds__(256, 4) void k_conv_mfma(
    const bf16* __restrict__ vt, const bf16* __restrict__ at, bf16* __restrict__ ud1t)
{
    __shared__ unsigned short ash2[2][2068];  // reversed filter, 2 shifted copies
    __shared__ unsigned short vsh[4][3072];   // per-batch v, stride 24 per 16-elem tile

    const int tid = threadIdx.x, lane = tid & 63, w = tid >> 6;
    const int c = blockIdx.x;

    {
        const unsigned short* asrc = (const unsigned short*)(at + (size_t)c * 2048);
        for (int i = tid; i < 2068; i += 256) {
#pragma unroll
            for (int k = 0; k < 2; ++k) {
                int src = 2047 - i - k;
                ash2[k][i] = (src >= 0) ? asrc[src] : (unsigned short)0;
            }
        }
    }
    {
        const bf16* vsrc = vt + ((size_t)w * 1024 + c) * 2048;
#pragma unroll
        for (int q = 0; q < 4; ++q) {
            int li = q * 64 + lane;
            int tile = li >> 1, hf = li & 1;
            *(uint4*)(void*)&vsh[w][tile * 24 + hf * 8] =
                *(const uint4*)(const void*)(vsrc + li * 8);
        }
    }
    __syncthreads();

    const int lm = lane & 15, lq = lane >> 4;
    const int h = lq >> 1, p0 = (lq & 1) * 8;
    const int kcopy = (lm + 1) & 1;
    const int base = 31 - 16 * h - lm + p0 - kcopy;
    const unsigned int* aw = (const unsigned int*)(void*)&ash2[kcopy][0] + (base >> 1);
    const unsigned short* vw = &vsh[w][0];

    f32x4 acc[8];
    f32x4 zz = {0.f, 0.f, 0.f, 0.f};
#pragma unroll
    for (int i = 0; i < 8; ++i) acc[i] = zz;
    const bf16x8 zfrag = (bf16x8)(short)0;

    for (int d2 = 0; d2 < 16; d2 += 2) {
        bf16x8 vf[8];
        const int tb = lm - d2 - h;
        {
            int T = tb > 0 ? tb : 0;
            bf16x8 f = *(const bf16x8*)(const void*)(vw + T * 24 + p0);
            vf[0] = (tb < 0) ? zfrag : f;
        }
#pragma unroll
        for (int dl = 1; dl < 8; ++dl)
            vf[dl] = *(const bf16x8*)(const void*)(vw + (dl * 16 + tb) * 24 + p0);

#pragma unroll
        for (int dt = 0; dt < 8; ++dt) {
            const int m16 = (63 - ((dt * 16 + d2) >> 1)) * 16;
            union { unsigned int u[4]; bf16x8 v; } af;
            af.u[0] = aw[m16 + 0];
            af.u[1] = aw[m16 + 1];
            af.u[2] = aw[m16 + 2];
            af.u[3] = aw[m16 + 3];
#pragma unroll
            for (int dl = 0; dl < 8 - dt; ++dl)
                acc[dt + dl] = __builtin_amdgcn_mfma_f32_16x16x32_bf16(af.v, vf[dl], acc[dt + dl], 0, 0, 0);
        }
    }

    __syncthreads();
    float* stg = (float*)(void*)((char*)(void*)&ash2[0][0] + w * 1024);
    bf16* dst = ud1t + ((size_t)w * 1024 + c) * 2048;
#pragma unroll
    for (int jg = 0; jg < 8; ++jg) {
        *(f32x4*)(void*)&stg[lm * 16 + lq * 4] = acc[jg];
        f32x4 vv = *(const f32x4*)(const void*)&stg[lane * 4];
        uint2 o;
        o.x = packbf2(vv.x, vv.y);
        o.y = packbf2(vv.z, vv.w);
        *(uint2*)(void*)(dst + jg * 256 + lane * 4) = o;
    }
}

extern "C" void kernel_launch(void* const* d_in, const int* in_sizes, int n_in,
                              void* d_out, int out_size, void* d_ws, size_t ws_size,
                              hipStream_t stream)
{
    const float* x  = (const float*)d_in[0];
    const float* Wu = (const float*)d_in[1];
    const float* bu = (const float*)d_in[2];
    const float* Wv = (const float*)d_in[3];
    const float* bv = (const float*)d_in[4];
    const float* Wo = (const float*)d_in[5];
    const float* bo = (const float*)d_in[6];
    const float* Wp = (const float*)d_in[7];
    const float* bp = (const float*)d_in[8];
    const float* W1 = (const float*)d_in[9];
    const float* b1 = (const float*)d_in[10];
    const float* W2 = (const float*)d_in[11];
    const float* b2 = (const float*)d_in[12];
    const float* W3 = (const float*)d_in[13];
    const float* b3 = (const float*)d_in[14];
    const float* Wz = (const float*)d_in[15];
    const float* bz = (const float*)d_in[16];

    char* p = (char*)d_ws;
    auto carve = [&](size_t bytes) { void* q = (void*)p; p += (bytes + 255) & ~(size_t)255; return q; };
    bf16*  xn   = (bf16*)carve((size_t)8192 * 512 * 2);
    bf16*  Wuvt = (bf16*)carve((size_t)2048 * 512 * 2);
    bf16*  Wot  = (bf16*)carve((size_t)512 * 1024 * 2);
    bf16*  Wf   = (bf16*)carve((size_t)5 * 262144 * 2);       // fragment-major MLP weights
    bf16*  uvb  = (bf16*)carve((size_t)8192 * 2048 * 2);      // u silu output (t, c); v-half unused
    bf16*  ud1  = (bf16*)carve((size_t)8192 * 1024 * 2);      // u * conv, (t, c)
    bf16*  vtb  = (bf16*)carve((size_t)4 * 1024 * 2048 * 2);  // v (b,c,t)
    bf16*  atb  = (bf16*)carve((size_t)1024 * 2048 * 2);      // a (c,k)
    bf16*  ud1t = (bf16*)carve((size_t)4 * 1024 * 2048 * 2);  // conv result (b,c,t)

    // fused prologue: weight transposes + MLP weight prep + rms(x)
    PrepArgs pa;
    const float* srcs[3] = {Wu, Wv, Wo};
    bf16* dsts[3] = {Wuvt, Wuvt + (size_t)1024 * 512, Wot};
    int Rs[3] = {512, 512, 1024};
    int Cs[3] = {1024, 1024, 512};
    int acc_t = 0;
    for (int i = 0; i < 3; ++i) {
        pa.src[i] = srcs[i]; pa.dst[i] = dsts[i]; pa.R[i] = Rs[i]; pa.C[i] = Cs[i];
        pa.pfx[i] = acc_t;
        acc_t += (Rs[i] / 32) * (Cs[i] / 32);
    }
    pa.pfx[3] = acc_t;  // 1536
    k_prologue<<<1536 + 640 + 8192, 256, 0, stream>>>(pa, W1, W2, W3, Wz, Wf, x, xn);

    // fused: positional MLP (64 blocks) + uv GEMM (1024 blocks), 1024 threads
    k_uv_mlp2<<<1088, 1024, 0, stream>>>(xn, Wuvt, bu, bv, Wp, bp,
                                         Wf, b1, b2, b3, bz, uvb, vtb, atb);

    // causal depthwise conv via Toeplitz-MFMA (block = channel x 4 batches)
    k_conv_mfma<<<dim3(1024), 256, 0, stream>>>(vtb, atb, ud1t);

    // gate by u and transpose back to (t, c) — vectorized
    k_gate_transpose<<<dim3(16, 32, 4), 256, 0, stream>>>(ud1t, uvb, ud1);

    // y = ud1 @ Wo + bo + x  (async dbuf structure, 512 blocks)
    k_gemm_out2<<<dim3(128, 4), 256, 0, stream>>>(ud1, Wot, bo, x, (float*)d_out);
}